// Round 3
// baseline (191.844 us; speedup 1.0000x reference)
//
#include <hip/hip_runtime.h>
#include <math.h>

#define RESERVOIR 8192
#define WINDOW 96
#define PRED 96
#define SEGMENTS 4096
#define TC 512                      /* segments per chunk */
#define NCHUNK (SEGMENTS / TC)      /* 8 */
#define CLAMP_C 3.4f

typedef unsigned short u16;
typedef unsigned int u32;
typedef __attribute__((ext_vector_type(8))) short bf16x8;
typedef __attribute__((ext_vector_type(4))) float floatx4;

__device__ __forceinline__ u16 f2bf(float f) {
    u32 u = __float_as_uint(f);
    return (u16)((u + 0x7fffu + ((u >> 16) & 1u)) >> 16);
}
__device__ __forceinline__ u32 packbf(float a, float b) {
    return (u32)f2bf(a) | ((u32)f2bf(b) << 16);
}

// ---------------------------------------------------------------------------
// prep: pack Win and x into fragment-ordered bf16 hi/lo arrays + zero state.
// Fragment map (16-row x 32-k tile): lane l -> row l&15, k = kt*32+4*(l>>4)+{0..3,+16}.
// ---------------------------------------------------------------------------
__global__ __launch_bounds__(256) void prep_kernel(const float* __restrict__ x,
                                                   const float* __restrict__ Win,
                                                   u16* __restrict__ Wph, u16* __restrict__ Wpl,
                                                   u16* __restrict__ Xph, u16* __restrict__ Xpl,
                                                   float* __restrict__ s_ws) {
    const int gid = blockIdx.x * 256 + threadIdx.x;
    const float* src;
    u16 *dh, *dl;
    int idx;
    if (blockIdx.x < 384) {            // Win: 512 row-tiles x 3 kt x 64 lanes
        idx = gid;
        const int tile = idx >> 6, lane = idx & 63;
        const int rt = tile / 3, kt = tile % 3;
        src = Win + (size_t)(rt * 16 + (lane & 15)) * WINDOW + kt * 32 + 4 * (lane >> 4);
        dh = Wph; dl = Wpl;
    } else if (blockIdx.x < 576) {     // x: 256 seg-tiles x 3 kt x 64 lanes
        idx = gid - 384 * 256;
        const int tile = idx >> 6, lane = idx & 63;
        const int rt = tile / 3, kt = tile % 3;
        src = x + (size_t)(rt * 16 + (lane & 15)) * WINDOW + kt * 32 + 4 * (lane >> 4);
        dh = Xph; dl = Xpl;
    } else {                           // zero state
        s_ws[gid - 576 * 256] = 0.f;
        return;
    }
    const float4 v0 = *(const float4*)(src);
    const float4 v1 = *(const float4*)(src + 16);
    const float f[8] = {v0.x, v0.y, v0.z, v0.w, v1.x, v1.y, v1.z, v1.w};
    u16 h[8], l[8];
#pragma unroll
    for (int j = 0; j < 8; ++j) {
        h[j] = f2bf(f[j]);
        l[j] = f2bf(f[j] - __uint_as_float((u32)h[j] << 16));
    }
    *(uint4*)(dh + (size_t)idx * 8) = make_uint4(h[0] | (u32)h[1] << 16, h[2] | (u32)h[3] << 16,
                                                 h[4] | (u32)h[5] << 16, h[6] | (u32)h[7] << 16);
    *(uint4*)(dl + (size_t)idx * 8) = make_uint4(l[0] | (u32)l[1] << 16, l[2] | (u32)l[3] << 16,
                                                 l[4] | (u32)l[5] << 16, l[6] | (u32)l[7] << 16);
}

// ---------------------------------------------------------------------------
// rec: 8192 chains. Per step (all plain VALU, chain depth 6 ~24 cyc):
//   zc = med3(z, -C, C); t = zc^2; P = Estrin-deg15(t); z = fma(d*zc, P, y_next)
// Y packed as u32 = two bf16 steps. 3-buffer rotation, 2-slab prefetch.
// ---------------------------------------------------------------------------
__device__ __forceinline__ void rec_path(const u32* __restrict__ Yin,
                                         const float* __restrict__ dvec,
                                         float* __restrict__ s_ws,
                                         float c0, float c1, float c2, float c3,
                                         float c4, float c5, float c6, float c7) {
    __builtin_amdgcn_s_setprio(1);
    const int tid = blockIdx.x * 256 + threadIdx.x;
    const float dd = dvec[tid];
    const float s0 = s_ws[tid];
    const u32* p = Yin + tid;
    u32 A[16], B[16], C[16];
#define LOADS(buf, s) { _Pragma("unroll") for (int j = 0; j < 16; ++j) buf[j] = p[(size_t)((s) * 16 + j) * RESERVOIR]; }
#define BLO(r) __uint_as_float((r) << 16)
#define BHI(r) __uint_as_float((r) & 0xffff0000u)
#define STEP(yv) { const float zc = __builtin_amdgcn_fmed3f(z, -CLAMP_C, CLAMP_C); \
    const float tt = zc * zc; const float uu = dd * zc; \
    const float p01 = fmaf(tt, c1, c0), p23 = fmaf(tt, c3, c2); \
    const float p45 = fmaf(tt, c5, c4), p67 = fmaf(tt, c7, c6); \
    const float t2 = tt * tt; \
    const float q0 = fmaf(t2, p23, p01), q1 = fmaf(t2, p67, p45); \
    const float t4 = t2 * t2; \
    z = fmaf(uu, fmaf(t4, q1, q0), (yv)); }
#define STEP32(buf) { _Pragma("unroll") for (int j = 0; j < 16; ++j) { STEP(BLO(buf[j])); STEP(BHI(buf[j])); } }
    LOADS(A, 0) LOADS(B, 1) LOADS(C, 2)
    float z = fmaf(dd, s0, BLO(A[0]));
    STEP(BHI(A[0]));
#pragma unroll
    for (int j = 1; j < 16; ++j) { STEP(BLO(A[j])); STEP(BHI(A[j])); }
    LOADS(A, 3)
    for (int g = 0; g < 5; ++g) {      // slabs 3g+1(B), 3g+2(C), 3g+3(A)
        STEP32(B) if (g < 4) LOADS(B, 3 * g + 4)
        STEP32(C) if (g < 4) LOADS(C, 3 * g + 5)
        STEP32(A) if (g < 4) LOADS(A, 3 * g + 6)
    }
    // final tanh of last z
    const float zc = __builtin_amdgcn_fmed3f(z, -CLAMP_C, CLAMP_C);
    const float tt = zc * zc;
    const float p01 = fmaf(tt, c1, c0), p23 = fmaf(tt, c3, c2);
    const float p45 = fmaf(tt, c5, c4), p67 = fmaf(tt, c7, c6);
    const float t2 = tt * tt;
    const float q0 = fmaf(t2, p23, p01), q1 = fmaf(t2, p67, p45);
    const float t4 = t2 * t2;
    s_ws[tid] = zc * fmaf(t4, q1, q0);
#undef LOADS
#undef STEP32
#undef STEP
#undef BLO
#undef BHI
}

// ---------------------------------------------------------------------------
// gemm: bf16x3-split MFMA. Block = 4 waves (2 t x 2 i), wave = 64t x 64i.
// Y written as u32 = bf16 pair (even t low, odd t high), rows = t/2.
// ---------------------------------------------------------------------------
__device__ __forceinline__ void gemm_path(int bid, int chunk,
                                          const u16* __restrict__ Xph, const u16* __restrict__ Xpl,
                                          const u16* __restrict__ Wph, const u16* __restrict__ Wpl,
                                          u32* __restrict__ Yout) {
    const int lane = threadIdx.x & 63;
    const int wave = threadIdx.x >> 6;
    const int wt = wave >> 1, wi = wave & 1;
    const int tb = bid >> 6, ib = bid & 63;              // 4 t-blocks x 64 i-blocks
    const int tt0 = chunk * (TC / 16) + tb * 8 + wt * 4; // global t-frag-tile
    const int it0 = ib * 8 + wi * 4;

    floatx4 acc[4][4];
#pragma unroll
    for (int m = 0; m < 4; ++m)
#pragma unroll
        for (int n = 0; n < 4; ++n) acc[m][n] = (floatx4)0.f;

#pragma unroll
    for (int kt = 0; kt < 3; ++kt) {
        bf16x8 ah[4], al[4], bh[4], bl[4];
#pragma unroll
        for (int m = 0; m < 4; ++m) {
            const size_t ax = ((size_t)((tt0 + m) * 3 + kt) * 64 + lane) * 8;
            ah[m] = *(const bf16x8*)(Xph + ax);
            al[m] = *(const bf16x8*)(Xpl + ax);
            const size_t bx = ((size_t)((it0 + m) * 3 + kt) * 64 + lane) * 8;
            bh[m] = *(const bf16x8*)(Wph + bx);
            bl[m] = *(const bf16x8*)(Wpl + bx);
        }
#pragma unroll
        for (int m = 0; m < 4; ++m)
#pragma unroll
            for (int n = 0; n < 4; ++n) {
                acc[m][n] = __builtin_amdgcn_mfma_f32_16x16x32_bf16(ah[m], bh[n], acc[m][n], 0, 0, 0);
                acc[m][n] = __builtin_amdgcn_mfma_f32_16x16x32_bf16(ah[m], bl[n], acc[m][n], 0, 0, 0);
                acc[m][n] = __builtin_amdgcn_mfma_f32_16x16x32_bf16(al[m], bh[n], acc[m][n], 0, 0, 0);
            }
    }

    const int g = lane >> 4, cc = lane & 15;
#pragma unroll
    for (int m = 0; m < 4; ++m) {
        const int trow0 = (tb * 8 + wt * 4 + m) * 16 + 4 * g;   // chunk-local t, mult of 4
        const int row2 = trow0 >> 1;
#pragma unroll
        for (int n = 0; n < 4; ++n) {
            const int col = (it0 + n) * 16 + cc;
            Yout[(size_t)(row2 + 0) * RESERVOIR + col] = packbf(acc[m][n][0], acc[m][n][1]);
            Yout[(size_t)(row2 + 1) * RESERVOIR + col] = packbf(acc[m][n][2], acc[m][n][3]);
        }
    }
}

__global__ __launch_bounds__(256) void main_kernel(const u16* __restrict__ Xph, const u16* __restrict__ Xpl,
                                                   const u16* __restrict__ Wph, const u16* __restrict__ Wpl,
                                                   u32* __restrict__ Yout, const u32* __restrict__ Yin,
                                                   const float* __restrict__ dvec, float* __restrict__ s_ws,
                                                   int chunk, int n_rec,
                                                   float c0, float c1, float c2, float c3,
                                                   float c4, float c5, float c6, float c7) {
    if ((int)blockIdx.x < n_rec) {
        rec_path(Yin, dvec, s_ws, c0, c1, c2, c3, c4, c5, c6, c7);
        return;
    }
    gemm_path(blockIdx.x - n_rec, chunk, Xph, Xpl, Wph, Wpl, Yout);
}

// ---------------------------------------------------------------------------
// out projection: out[p] = dot(W_out[p,:], s)
// ---------------------------------------------------------------------------
__global__ __launch_bounds__(256) void out_kernel(const float* __restrict__ Wout,
                                                  const float* __restrict__ s,
                                                  float* __restrict__ out) {
    const int p = blockIdx.x;
    const int tid = threadIdx.x;
    float acc = 0.f;
#pragma unroll
    for (int j = 0; j < 8; ++j) {
        const int idx = (j * 256 + tid) * 4;
        const float4 w = *(const float4*)(Wout + (size_t)p * RESERVOIR + idx);
        const float4 sv = *(const float4*)(s + idx);
        acc = fmaf(w.x, sv.x, acc);
        acc = fmaf(w.y, sv.y, acc);
        acc = fmaf(w.z, sv.z, acc);
        acc = fmaf(w.w, sv.w, acc);
    }
#pragma unroll
    for (int off = 32; off > 0; off >>= 1) acc += __shfl_down(acc, off);
    __shared__ float red[4];
    if ((tid & 63) == 0) red[tid >> 6] = acc;
    __syncthreads();
    if (tid == 0) out[p] = red[0] + red[1] + red[2] + red[3];
}

// ---------------------------------------------------------------------------
// Host: Chebyshev fit of tanh(C*v) on v in [-1,1], odd degree 15 -> monomial
// coeffs c[j] of P(t): tanh(z) ~ zc * P(zc^2). Deterministic, runs per launch.
// ---------------------------------------------------------------------------
static void tanh_coeffs(double Cd, float c[8]) {
    const int N = 256, NC = 8;
    double a[NC];
    for (int j = 0; j < NC; ++j) a[j] = 0.0;
    for (int k = 0; k < N; ++k) {
        const double th = M_PI * (k + 0.5) / N;
        const double v = cos(th), gg = tanh(Cd * v);
        for (int j = 0; j < NC; ++j) a[j] += gg * cos((2 * j + 1) * th);
    }
    for (int j = 0; j < NC; ++j) a[j] *= 2.0 / N;
    double mono[16];
    for (int m = 0; m < 16; ++m) mono[m] = 0.0;
    double Tp[17], Tc[17], Tn[17];
    for (int m = 0; m < 17; ++m) { Tp[m] = 0; Tc[m] = 0; }
    Tp[0] = 1.0; Tc[1] = 1.0;
    mono[1] += a[0];                       // a0 * T1
    for (int n = 1; n <= 14; ++n) {        // build T_{n+1}
        for (int m = 0; m < 17; ++m) Tn[m] = -Tp[m];
        for (int m = 0; m < 16; ++m) Tn[m + 1] += 2.0 * Tc[m];
        for (int m = 0; m < 17; ++m) { Tp[m] = Tc[m]; Tc[m] = Tn[m]; }
        const int deg = n + 1;
        if (deg & 1) {
            const int j = deg >> 1;
            if (j < NC)
                for (int m = 0; m <= deg; ++m) mono[m] += a[j] * Tc[m];
        }
    }
    double Cp = Cd;
    for (int j = 0; j < 8; ++j) { c[j] = (float)(mono[2 * j + 1] / Cp); Cp *= Cd * Cd; }
}

extern "C" void kernel_launch(void* const* d_in, const int* in_sizes, int n_in,
                              void* d_out, int out_size, void* d_ws, size_t ws_size,
                              hipStream_t stream) {
    (void)in_sizes; (void)n_in; (void)out_size; (void)ws_size;
    const float* x    = (const float*)d_in[0];
    const float* Win  = (const float*)d_in[1];
    const float* dvec = (const float*)d_in[2];
    const float* Wout = (const float*)d_in[3];
    float* out = (float*)d_out;

    float pc[8];
    tanh_coeffs((double)CLAMP_C, pc);

    // ws layout (~21.5 MB)
    char* w = (char*)d_ws;
    const size_t ybytes = (size_t)(TC / 2) * RESERVOIR * 4;    // 8 MiB each
    u32* Y0 = (u32*)w;
    u32* Y1 = (u32*)(w + ybytes);
    float* s_ws = (float*)(w + 2 * ybytes);
    u16* Xph = (u16*)(w + 2 * ybytes + RESERVOIR * 4);
    u16* Xpl = Xph + (size_t)SEGMENTS * WINDOW;
    u16* Wph = Xpl + (size_t)SEGMENTS * WINDOW;
    u16* Wpl = Wph + (size_t)RESERVOIR * WINDOW;

    prep_kernel<<<608, 256, 0, stream>>>(x, Win, Wph, Wpl, Xph, Xpl, s_ws);
    // chunk 0 gemm only (256 blocks)
    main_kernel<<<256, 256, 0, stream>>>(Xph, Xpl, Wph, Wpl, Y0, nullptr, dvec, s_ws, 0, 0,
                                         pc[0], pc[1], pc[2], pc[3], pc[4], pc[5], pc[6], pc[7]);
    // fused: rec(c-1) || gemm(c)
    for (int c = 1; c < NCHUNK; ++c) {
        u32* Yo = (c & 1) ? Y1 : Y0;
        u32* Yi = (c & 1) ? Y0 : Y1;
        main_kernel<<<288, 256, 0, stream>>>(Xph, Xpl, Wph, Wpl, Yo, Yi, dvec, s_ws, c, 32,
                                             pc[0], pc[1], pc[2], pc[3], pc[4], pc[5], pc[6], pc[7]);
    }
    // final rec (chunk 7 lives in Y1)
    main_kernel<<<32, 256, 0, stream>>>(Xph, Xpl, Wph, Wpl, nullptr, Y1, dvec, s_ws, 0, 32,
                                        pc[0], pc[1], pc[2], pc[3], pc[4], pc[5], pc[6], pc[7]);
    out_kernel<<<PRED, 256, 0, stream>>>(Wout, s_ws, out);
}